// Round 4
// baseline (336.627 us; speedup 1.0000x reference)
//
#include <hip/hip_runtime.h>
#include <hip/hip_fp16.h>

#define WIDTH   640
#define HEIGHT  384
#define PLANE   (WIDTH*HEIGHT)
#define STRIP_H 12
#define NSTRIP  32                /* 384/12 */
#define GROUPS  6                 /* STRIP_H/2 */
#define NBLK    (96*NSTRIP)       /* 3072 = 3 perfect rounds of 4 blocks/CU */
#define CS_W    656               /* slots 0..649 used, slot = x+5 */
#define SSIM_C1 1.0e-4f
#define SSIM_C2 9.0e-4f
#define INV_N   (1.0f/23592960.0f)

__device__ __forceinline__ unsigned packh2(float a, float b) {
    // single v_cvt_pkrtz_f16_f32; rtz quantization is consistent add/sub so no drift
    __fp16 __attribute__((ext_vector_type(2))) v = __builtin_amdgcn_cvt_pkrtz(a, b);
    unsigned r; __builtin_memcpy(&r, &v, 4); return r;
}
__device__ __forceinline__ float2 unpackh2(unsigned u) {
    __fp16 __attribute__((ext_vector_type(2))) v;
    __builtin_memcpy(&v, &u, 4);
    return make_float2((float)v.x, (float)v.y);
}

// 4 waves/EU cap -> 128 VGPRs: ring(36) + S(12) + pf(12) + base(~60) fits.
// (Round-2 lesson: at cap 84 the ring demotes to scratch; at 128 it must not.)
__global__ __launch_bounds__(256, 4)
void ssim_main(const float* __restrict__ pred, const float* __restrict__ targ,
               float* __restrict__ ws)
{
    // SoA column sums only in LDS (21 KB): Phase-A writes stride-1 b32 (free),
    // Phase-B reads stride-5 b32 (gcd(5,32)=1 -> free). Proven: conflicts ~0.
    __shared__ float cs[4][2][CS_W];   // [comp][k][slot]: Sp, St, Spp+Stt, Spt
    __shared__ float red[4];

    const int tid   = threadIdx.x;
    const int plane = blockIdx.x % 96;    // vertical neighbors differ by 96 -> same XCD
    const int strip = blockIdx.x / 96;    // 0..31
    const int y0s   = strip * STRIP_H;
    const float* __restrict__ P = pred + plane * PLANE;
    const float* __restrict__ T = targ + plane * PLANE;

    // zero horizontal-halo cs slots once (Phase A never touches them; first
    // Phase-B read is after the first barrier, which orders this write)
    if (tid < 80) {
        int comp = tid / 20, k = (tid / 10) & 1, j = tid % 10;
        int s = (j < 5) ? j : (640 + j);   // {0..4, 645..649}
        cs[comp][k][s] = 0.f;
    }

    // ---- Register ring: 12-deep fp16x2 (p,t) history per column.
    //      All slot indices are compile-time constants (GROUPS=6 = ring period,
    //      group loop fully unrolled) -> must stay in VGPRs.
    unsigned ring[3][12];
    float S[3][4];
#pragma unroll
    for (int c = 0; c < 3; ++c) {
        S[c][0]=S[c][1]=S[c][2]=S[c][3]=0.f;
        ring[c][0] = 0u;
    }

    // Bootstrap: rows [y0s-6, y0s+4] -> ring slots 1..11, column sums for the
    // window of output row y0s-1 (all arithmetic on the quantized fp16 values)
#pragma unroll
    for (int c = 0; c < 3; ++c) {
        int x = tid + (c << 8);
        if (x < WIDTH) {
#pragma unroll
            for (int j = 0; j < 11; ++j) {
                int yy = y0s - 6 + j;
                unsigned h = 0u;
                if (yy >= 0) h = packh2(P[yy*WIDTH + x], T[yy*WIDTH + x]);
                ring[c][j + 1] = h;
                float2 v = unpackh2(h);
                S[c][0] += v.x;  S[c][1] += v.y;
                S[c][2] += v.x*v.x + v.y*v.y;
                S[c][3] += v.x*v.y;
            }
        } else {
#pragma unroll
            for (int j = 0; j < 11; ++j) ring[c][j + 1] = 0u;
        }
    }

    // prefetch registers for the two rows entering the window each group
    float pfP[3][2], pfT[3][2];
    auto do_prefetch = [&](int gg) {
        const int y0 = y0s + (gg << 1);
#pragma unroll
        for (int c = 0; c < 3; ++c) {
            int x = tid + (c << 8);
            if (x < WIDTH) {
#pragma unroll
                for (int k = 0; k < 2; ++k) {
                    int yn = y0 + k + 5;
                    bool v = (yn < HEIGHT);
                    pfP[c][k] = v ? P[yn*WIDTH + x] : 0.f;
                    pfT[c][k] = v ? T[yn*WIDTH + x] : 0.f;
                }
            }
        }
    };
    do_prefetch(0);

    float acc = 0.f;
    const float inv121 = 1.0f / 121.0f;
    const int r    = tid >> 6;
    const int lane = tid & 63;
    const int kb   = r & 1;
    const int base = ((r >> 1) * 320) + lane * 5;   // slots [base, base+14]

#pragma unroll
    for (int g = 0; g < GROUPS; ++g) {
        // consume this group's prefetched rows into locals, then issue next
        // group's loads -> VMEM latency overlaps rest of A + barrier + B
        float cP[3][2], cT[3][2];
#pragma unroll
        for (int c = 0; c < 3; ++c)
#pragma unroll
            for (int k = 0; k < 2; ++k) { cP[c][k] = pfP[c][k]; cT[c][k] = pfT[c][k]; }

        if (g + 1 < GROUPS) do_prefetch(g + 1);

        // ---- Phase A: advance 2 rows; ring slots compile-time constants
#pragma unroll
        for (int c = 0; c < 3; ++c) {
            int x = tid + (c << 8);
            if (x < WIDTH) {
#pragma unroll
                for (int k = 0; k < 2; ++k) {
                    const int sNew = 2*g + k;            // write slot
                    const int sOld = (2*g + k + 1) % 12; // leaving row
                    unsigned hn = packh2(cP[c][k], cT[c][k]);
                    unsigned ho = ring[c][sOld];
                    ring[c][sNew] = hn;
                    float2 nq = unpackh2(hn);   // use quantized value
                    float2 o  = unpackh2(ho);
                    S[c][0] += nq.x - o.x;
                    S[c][1] += nq.y - o.y;
                    S[c][2] += nq.x*nq.x + nq.y*nq.y - o.x*o.x - o.y*o.y;
                    S[c][3] += nq.x*nq.y - o.x*o.y;
                    cs[0][k][x + 5] = S[c][0];
                    cs[1][k][x + 5] = S[c][1];
                    cs[2][k][x + 5] = S[c][2];
                    cs[3][k][x + 5] = S[c][3];
                }
            }
        }
        __syncthreads();

        // ---- Phase B: 4 waves = 2 rows x 2 halves; 5 px/lane; rolling
        //      11-window, all b32 at lane-stride 5 dwords (conflict-free);
        //      constant offsets from one base -> ds_read2_b32 merging
        {
            float B0=0.f, B1=0.f, B2=0.f, B3=0.f;
#pragma unroll
            for (int j = 0; j < 11; ++j) {
                B0 += cs[0][kb][base + j];
                B1 += cs[1][kb][base + j];
                B2 += cs[2][kb][base + j];
                B3 += cs[3][kb][base + j];
            }
#pragma unroll
            for (int i = 0; i < 5; ++i) {
                if (i > 0) {
                    B0 += cs[0][kb][base + 10 + i] - cs[0][kb][base + i - 1];
                    B1 += cs[1][kb][base + 10 + i] - cs[1][kb][base + i - 1];
                    B2 += cs[2][kb][base + 10 + i] - cs[2][kb][base + i - 1];
                    B3 += cs[3][kb][base + 10 + i] - cs[3][kb][base + i - 1];
                }
                float mp  = B0 * inv121, mt = B1 * inv121;
                float mpp = mp*mp, mtt = mt*mt, mpt = mp*mt;
                float s2  = B2 * inv121 - mpp - mtt;   // sigma_p + sigma_t
                float spt = B3 * inv121 - mpt;         // sigma_pt
                float num = (2.f*mpt + SSIM_C1) * (2.f*spt + SSIM_C2);
                float den = (mpp + mtt + SSIM_C1) * (s2 + SSIM_C2);
                acc += num * __builtin_amdgcn_rcpf(den);
            }
        }
        __syncthreads();
    }

    // ---- block reduction -> one plain store per block (no atomics)
#pragma unroll
    for (int off = 32; off >= 1; off >>= 1)
        acc += __shfl_down(acc, off);
    if ((tid & 63) == 0) red[tid >> 6] = acc;
    __syncthreads();
    if (tid == 0)
        ws[blockIdx.x] = red[0] + red[1] + red[2] + red[3];
}

__global__ void ssim_reduce(const float* __restrict__ ws, float* __restrict__ out)
{
    __shared__ float red[4];
    const int tid = threadIdx.x;
    float s = 0.f;
#pragma unroll
    for (int i = 0; i < 12; ++i) s += ws[tid + (i << 8)];
#pragma unroll
    for (int off = 32; off >= 1; off >>= 1)
        s += __shfl_down(s, off);
    if ((tid & 63) == 0) red[tid >> 6] = s;
    __syncthreads();
    if (tid == 0)
        out[0] = 1.0f - (red[0] + red[1] + red[2] + red[3]) * INV_N;
}

extern "C" void kernel_launch(void* const* d_in, const int* in_sizes, int n_in,
                              void* d_out, int out_size, void* d_ws, size_t ws_size,
                              hipStream_t stream) {
    const float* pred = (const float*)d_in[0];
    const float* targ = (const float*)d_in[1];
    float* out = (float*)d_out;
    float* ws  = (float*)d_ws;          // 3072 floats of partial sums
    ssim_main<<<NBLK, 256, 0, stream>>>(pred, targ, ws);
    ssim_reduce<<<1, 256, 0, stream>>>(ws, out);
}

// Round 5
// 228.886 us; speedup vs baseline: 1.4707x; 1.4707x over previous
//
#include <hip/hip_runtime.h>
#include <hip/hip_fp16.h>

#define WIDTH   640
#define HEIGHT  384
#define PLANE   (WIDTH*HEIGHT)
#define STRIP_H 48
#define NSTRIP  8                 /* 384/48 */
#define GROUPS  24                /* STRIP_H/2 */
#define NBLK    (96*NSTRIP)       /* 768 = 3 blocks/CU exactly */
#define SEG     160               /* output cols per wave */
#define LCOLS   170               /* owned cols incl 5-col halo each side */
#define LDW     172               /* padded stride (172 mod 32 = 12 -> B reads 2-way max) */
#define SSIM_C1 1.0e-4f
#define SSIM_C2 9.0e-4f
#define INV_N   (1.0f/23592960.0f)

__device__ __forceinline__ __half2 packh2(float a, float b) {
    // single v_cvt_pkrtz_f16_f32; rtz quantization is consistent add/sub so no drift
    __fp16 __attribute__((ext_vector_type(2))) v = __builtin_amdgcn_cvt_pkrtz(a, b);
    __half2 r;
    __builtin_memcpy(&r, &v, sizeof(r));
    return r;
}

// Wave-autonomous: each wave owns 160 output cols + 5-col halo (170 cols),
// with PRIVATE ring + cs LDS segments -> no inter-wave sharing -> the main
// loop has ZERO __syncthreads. Cross-lane A-write -> B-read visibility within
// a wave is ordered by s_waitcnt lgkmcnt(0) + compiler memory fence.
__global__ __launch_bounds__(256, 3)
void ssim_main(const float* __restrict__ pred, const float* __restrict__ targ,
               float* __restrict__ ws)
{
    __shared__ __half2 ring[4][11][LDW];   // per-wave raw (p,t) fp16 ring, 29.6 KB
    __shared__ float   cs[4][4][2][LDW];   // [wave][comp][k][o], 21.5 KB
    __shared__ float   red[4];

    const int tid   = threadIdx.x;
    const int w     = tid >> 6;             // wave 0..3
    const int lane  = tid & 63;
    const int plane = blockIdx.x % 96;      // vertical neighbors differ by 96 -> same XCD
    const int strip = blockIdx.x / 96;      // 0..7
    const int y0s   = strip * STRIP_H;
    const float* __restrict__ P = pred + plane * PLANE;
    const float* __restrict__ T = targ + plane * PLANE;
    const int wb = w * SEG - 5;             // image col of local offset 0 (may be <0)

    // lane owns local offsets oo = lane + 64m (m=0,1 always; m=2 iff lane<42)
    int  oo[3], cc[3];
    bool own[3], val[3];
#pragma unroll
    for (int m = 0; m < 3; ++m) {
        oo[m]  = lane + (m << 6);
        cc[m]  = wb + oo[m];
        own[m] = (oo[m] < LCOLS);
        val[m] = own[m] && (cc[m] >= 0) && (cc[m] < WIDTH);   // out-of-image cols stay 0
    }

    // ---- Bootstrap: rows [y0s-6, y0s+4] into private ring + column sums for
    //      the window of output row y0s-1 (arithmetic on quantized fp16)
    float S[3][4];
#pragma unroll
    for (int m = 0; m < 3; ++m) { S[m][0]=S[m][1]=S[m][2]=S[m][3]=0.f; }

#pragma unroll
    for (int m = 0; m < 3; ++m) {
        if (own[m]) {
#pragma unroll
            for (int j = 0; j < 11; ++j) {
                int yy = y0s - 6 + j;
                float p = 0.f, t = 0.f;
                if (val[m] && yy >= 0) { p = P[yy*WIDTH + cc[m]]; t = T[yy*WIDTH + cc[m]]; }
                __half2 h = packh2(p, t);
                ring[w][j][oo[m]] = h;
                float2 v = __half22float2(h);
                S[m][0] += v.x;  S[m][1] += v.y;
                S[m][2] += v.x*v.x + v.y*v.y;
                S[m][3] += v.x*v.y;
            }
        }
    }

    // prefetch registers for the two rows entering the window each group
    float pfP[3][2], pfT[3][2];
    auto do_prefetch = [&](int gg) {
        const int y0 = y0s + (gg << 1);
#pragma unroll
        for (int m = 0; m < 3; ++m) {
#pragma unroll
            for (int k = 0; k < 2; ++k) {
                int yn = y0 + k + 5;
                bool vy = val[m] && (yn < HEIGHT);
                pfP[m][k] = vy ? P[yn*WIDTH + cc[m]] : 0.f;
                pfT[m][k] = vy ? T[yn*WIDTH + cc[m]] : 0.f;
            }
        }
    };
    do_prefetch(0);

    float acc = 0.f;
    const float inv121 = 1.0f / 121.0f;
    const int kb   = lane >> 5;             // row within group
    const int base = (lane & 31) * 5;       // window slots [base, base+14]
    int rs = 0;   // ring slot of the row leaving/entering at k=0 of this group

#pragma clang loop unroll(disable)
    for (int g = 0; g < GROUPS; ++g) {
        // consume this group's prefetched rows, then immediately issue next
        // group's loads -> VMEM latency overlaps A + B (no barriers to wait at)
        float cP[3][2], cT[3][2];
#pragma unroll
        for (int m = 0; m < 3; ++m)
#pragma unroll
            for (int k = 0; k < 2; ++k) { cP[m][k] = pfP[m][k]; cT[m][k] = pfT[m][k]; }

        if (g + 1 < GROUPS) do_prefetch(g + 1);

        // WAR fence: last group's B reads retired before overwriting cs
        // (usually 0 outstanding by now -> ~free)
        asm volatile("s_waitcnt lgkmcnt(0)" ::: "memory");

        // ---- Phase A: advance 2 rows on this wave's private ring/cs
#pragma unroll
        for (int m = 0; m < 3; ++m) {
            if (own[m]) {
#pragma unroll
                for (int k = 0; k < 2; ++k) {
                    int slot = rs + k; if (slot >= 11) slot -= 11;
                    __half2 hn = packh2(cP[m][k], cT[m][k]);
                    __half2 ho = ring[w][slot][oo[m]];
                    ring[w][slot][oo[m]] = hn;
                    float2 nq = __half22float2(hn);   // use quantized value
                    float2 o2 = __half22float2(ho);
                    S[m][0] += nq.x - o2.x;
                    S[m][1] += nq.y - o2.y;
                    S[m][2] += nq.x*nq.x + nq.y*nq.y - o2.x*o2.x - o2.y*o2.y;
                    S[m][3] += nq.x*nq.y - o2.x*o2.y;
                    cs[w][0][k][oo[m]] = S[m][0];
                    cs[w][1][k][oo[m]] = S[m][1];
                    cs[w][2][k][oo[m]] = S[m][2];
                    cs[w][3][k][oo[m]] = S[m][3];
                }
            }
        }

        // RAW fence: this wave's cs writes visible before cross-lane reads
        asm volatile("s_waitcnt lgkmcnt(0)" ::: "memory");

        // ---- Phase B: 32 lanes x 2 rows x 5 px rolling 11-window; reads
        //      lane-stride 5 (gcd(5,32)=1) + k-offset 172 (==12 mod 32) -> free
        {
            float B0=0.f, B1=0.f, B2=0.f, B3=0.f;
#pragma unroll
            for (int j = 0; j < 11; ++j) {
                B0 += cs[w][0][kb][base + j];
                B1 += cs[w][1][kb][base + j];
                B2 += cs[w][2][kb][base + j];
                B3 += cs[w][3][kb][base + j];
            }
#pragma unroll
            for (int i = 0; i < 5; ++i) {
                if (i > 0) {
                    B0 += cs[w][0][kb][base + 10 + i] - cs[w][0][kb][base + i - 1];
                    B1 += cs[w][1][kb][base + 10 + i] - cs[w][1][kb][base + i - 1];
                    B2 += cs[w][2][kb][base + 10 + i] - cs[w][2][kb][base + i - 1];
                    B3 += cs[w][3][kb][base + 10 + i] - cs[w][3][kb][base + i - 1];
                }
                float mp  = B0 * inv121, mt = B1 * inv121;
                float mpp = mp*mp, mtt = mt*mt, mpt = mp*mt;
                float s2  = B2 * inv121 - mpp - mtt;   // sigma_p + sigma_t
                float spt = B3 * inv121 - mpt;         // sigma_pt
                float num = (2.f*mpt + SSIM_C1) * (2.f*spt + SSIM_C2);
                float den = (mpp + mtt + SSIM_C1) * (s2 + SSIM_C2);
                acc += num * __builtin_amdgcn_rcpf(den);
            }
        }

        rs += 2; if (rs >= 11) rs -= 11;
    }

    // ---- block reduction -> one plain store per block (no atomics)
#pragma unroll
    for (int off = 32; off >= 1; off >>= 1)
        acc += __shfl_down(acc, off);
    if (lane == 0) red[w] = acc;
    __syncthreads();
    if (tid == 0)
        ws[blockIdx.x] = red[0] + red[1] + red[2] + red[3];
}

__global__ void ssim_reduce(const float* __restrict__ ws, float* __restrict__ out)
{
    __shared__ float red[4];
    const int tid = threadIdx.x;
    float s = ws[tid] + ws[tid + 256] + ws[tid + 512];
#pragma unroll
    for (int off = 32; off >= 1; off >>= 1)
        s += __shfl_down(s, off);
    if ((tid & 63) == 0) red[tid >> 6] = s;
    __syncthreads();
    if (tid == 0)
        out[0] = 1.0f - (red[0] + red[1] + red[2] + red[3]) * INV_N;
}

extern "C" void kernel_launch(void* const* d_in, const int* in_sizes, int n_in,
                              void* d_out, int out_size, void* d_ws, size_t ws_size,
                              hipStream_t stream) {
    const float* pred = (const float*)d_in[0];
    const float* targ = (const float*)d_in[1];
    float* out = (float*)d_out;
    float* ws  = (float*)d_ws;          // 768 floats of partial sums
    ssim_main<<<NBLK, 256, 0, stream>>>(pred, targ, ws);
    ssim_reduce<<<1, 256, 0, stream>>>(ws, out);
}